// Round 1
// baseline (1423.816 us; speedup 1.0000x reference)
//
#include <hip/hip_runtime.h>
#include <math.h>

typedef __bf16 bf16_t;
typedef __bf16 bf16x8 __attribute__((ext_vector_type(8)));
typedef __bf16 bf16x4 __attribute__((ext_vector_type(4)));
typedef float f32x4 __attribute__((ext_vector_type(4)));

#define D_MODEL 2048
#define N_HEADS 16
#define HEAD_D 128
#define SEQ 2048
#define NTOK 4096   // B*T = 2*2048
#define DFF 8192    // D*MULT
#define UPN 16384   // 2*D*MULT

// ---------------- f32 -> bf16 convert (vectorized, grid-stride) ----------------
__global__ __launch_bounds__(256) void cvt_bf16_kernel(const float* __restrict__ in,
                                                       bf16_t* __restrict__ out, long n4) {
    long i = (long)blockIdx.x * 256 + threadIdx.x;
    long stride = (long)gridDim.x * 256;
    for (; i < n4; i += stride) {
        float4 f = ((const float4*)in)[i];
        bf16x4 v;
        v[0] = (bf16_t)f.x; v[1] = (bf16_t)f.y; v[2] = (bf16_t)f.z; v[3] = (bf16_t)f.w;
        ((bf16x4*)out)[i] = v;
    }
}

// ---------------- RMSNorm: one block per row of 2048, bf16 out ----------------
__global__ __launch_bounds__(256) void rmsnorm_kernel(const float* __restrict__ x,
                                                      const float* __restrict__ g,
                                                      bf16_t* __restrict__ out) {
    int row = blockIdx.x;
    const float* xr = x + (size_t)row * D_MODEL;
    int c0 = threadIdx.x * 8;
    float4 a = *(const float4*)&xr[c0];
    float4 b = *(const float4*)&xr[c0 + 4];
    float ss = a.x*a.x + a.y*a.y + a.z*a.z + a.w*a.w
             + b.x*b.x + b.y*b.y + b.z*b.z + b.w*b.w;
    #pragma unroll
    for (int off = 1; off < 64; off <<= 1) ss += __shfl_xor(ss, off);
    __shared__ float red[4];
    if ((threadIdx.x & 63) == 0) red[threadIdx.x >> 6] = ss;
    __syncthreads();
    float norm = rsqrtf((red[0] + red[1] + red[2] + red[3]) * (1.f / D_MODEL) + 1e-6f);
    float4 ga = *(const float4*)&g[c0];
    float4 gb = *(const float4*)&g[c0 + 4];
    bf16x8 o;
    o[0] = (bf16_t)(a.x * ga.x * norm); o[1] = (bf16_t)(a.y * ga.y * norm);
    o[2] = (bf16_t)(a.z * ga.z * norm); o[3] = (bf16_t)(a.w * ga.w * norm);
    o[4] = (bf16_t)(b.x * gb.x * norm); o[5] = (bf16_t)(b.y * gb.y * norm);
    o[6] = (bf16_t)(b.z * gb.z * norm); o[7] = (bf16_t)(b.w * gb.w * norm);
    *(bf16x8*)&out[(size_t)row * D_MODEL + c0] = o;
}

// ---------------- GEMM: C[M,N] = A[M,K] @ W[N,K]^T (row-major bf16) ----------------
// EPI 0: out bf16 = acc*alpha.  EPI 1: out f32 = res + acc.
template<int EPI>
__global__ __launch_bounds__(256)
void gemm_bt(const bf16_t* __restrict__ A, const bf16_t* __restrict__ W,
             void* __restrict__ outp, const float* __restrict__ res,
             int M, int N, int K, float alpha)
{
    __shared__ __align__(16) bf16_t As[128 * 32];
    __shared__ __align__(16) bf16_t Bs[128 * 32];
    const int tid = threadIdx.x;
    const int m0 = blockIdx.y * 128, n0 = blockIdx.x * 128;
    const int wave = tid >> 6, lane = tid & 63;
    const int wr = wave >> 1, wc = wave & 1;     // 2x2 wave grid, 64x64 per wave
    const int lr = lane & 15, lg = lane >> 4;
    f32x4 acc[4][4] = {};
    for (int k0 = 0; k0 < K; k0 += 32) {
        __syncthreads();
        #pragma unroll
        for (int i = 0; i < 2; ++i) {
            int v = tid + 256 * i;
            int row = v >> 2, cv = (v & 3) * 8;
            *(uint4*)&As[row * 32 + cv] = *(const uint4*)&A[(size_t)(m0 + row) * K + k0 + cv];
            *(uint4*)&Bs[row * 32 + cv] = *(const uint4*)&W[(size_t)(n0 + row) * K + k0 + cv];
        }
        __syncthreads();
        bf16x8 af[4], bfr[4];
        #pragma unroll
        for (int m = 0; m < 4; ++m) af[m] = *(const bf16x8*)&As[(wr * 64 + m * 16 + lr) * 32 + lg * 8];
        #pragma unroll
        for (int n = 0; n < 4; ++n) bfr[n] = *(const bf16x8*)&Bs[(wc * 64 + n * 16 + lr) * 32 + lg * 8];
        #pragma unroll
        for (int m = 0; m < 4; ++m)
            #pragma unroll
            for (int n = 0; n < 4; ++n)
                acc[m][n] = __builtin_amdgcn_mfma_f32_16x16x32_bf16(af[m], bfr[n], acc[m][n], 0, 0, 0);
    }
    #pragma unroll
    for (int m = 0; m < 4; ++m)
        #pragma unroll
        for (int n = 0; n < 4; ++n) {
            int row = m0 + wr * 64 + m * 16 + lg * 4;
            int col = n0 + wc * 64 + n * 16 + lr;
            #pragma unroll
            for (int r = 0; r < 4; ++r) {
                size_t idx = (size_t)(row + r) * N + col;
                float v = acc[m][n][r];
                if (EPI == 0) ((bf16_t*)outp)[idx] = (bf16_t)(v * alpha);
                else          ((float*)outp)[idx] = res[idx] + v;
            }
        }
}

// ---------------- Up-projection with fused GELU gate ----------------
// act[M, DFF] = gelu(A @ Wu^T) * (A @ Wv^T), Wu = w_up rows [0,DFF), Wv = rows [DFF,2*DFF)
__global__ __launch_bounds__(256)
void gemm_upgate(const bf16_t* __restrict__ A, const bf16_t* __restrict__ W,
                 bf16_t* __restrict__ act)
{
    __shared__ __align__(16) bf16_t As[128 * 32];
    __shared__ __align__(16) bf16_t Bu[64 * 32];
    __shared__ __align__(16) bf16_t Bv[64 * 32];
    const int tid = threadIdx.x;
    const int m0 = blockIdx.y * 128, n0 = blockIdx.x * 64;
    const int wave = tid >> 6, lane = tid & 63;
    const int wr = wave >> 1, wc = wave & 1;     // per wave: 64 rows x 32 cols (u and v)
    const int lr = lane & 15, lg = lane >> 4;
    f32x4 accu[4][2] = {}, accv[4][2] = {};
    for (int k0 = 0; k0 < D_MODEL; k0 += 32) {
        __syncthreads();
        #pragma unroll
        for (int i = 0; i < 2; ++i) {
            int v = tid + 256 * i;
            int row = v >> 2, cv = (v & 3) * 8;
            *(uint4*)&As[row * 32 + cv] = *(const uint4*)&A[(size_t)(m0 + row) * D_MODEL + k0 + cv];
        }
        {
            int row = tid >> 2, cv = (tid & 3) * 8;
            *(uint4*)&Bu[row * 32 + cv] = *(const uint4*)&W[(size_t)(n0 + row) * D_MODEL + k0 + cv];
            *(uint4*)&Bv[row * 32 + cv] = *(const uint4*)&W[(size_t)(DFF + n0 + row) * D_MODEL + k0 + cv];
        }
        __syncthreads();
        bf16x8 af[4], bu[2], bv[2];
        #pragma unroll
        for (int m = 0; m < 4; ++m) af[m] = *(const bf16x8*)&As[(wr * 64 + m * 16 + lr) * 32 + lg * 8];
        #pragma unroll
        for (int n = 0; n < 2; ++n) {
            bu[n] = *(const bf16x8*)&Bu[(wc * 32 + n * 16 + lr) * 32 + lg * 8];
            bv[n] = *(const bf16x8*)&Bv[(wc * 32 + n * 16 + lr) * 32 + lg * 8];
        }
        #pragma unroll
        for (int m = 0; m < 4; ++m)
            #pragma unroll
            for (int n = 0; n < 2; ++n) {
                accu[m][n] = __builtin_amdgcn_mfma_f32_16x16x32_bf16(af[m], bu[n], accu[m][n], 0, 0, 0);
                accv[m][n] = __builtin_amdgcn_mfma_f32_16x16x32_bf16(af[m], bv[n], accv[m][n], 0, 0, 0);
            }
    }
    #pragma unroll
    for (int m = 0; m < 4; ++m)
        #pragma unroll
        for (int n = 0; n < 2; ++n)
            #pragma unroll
            for (int r = 0; r < 4; ++r) {
                int row = m0 + wr * 64 + m * 16 + lg * 4 + r;
                int col = n0 + wc * 32 + n * 16 + lr;
                float u = accu[m][n][r], vg = accv[m][n][r];
                float ge = 0.5f * u * (1.f + erff(u * 0.70710678118654752f));
                act[(size_t)row * DFF + col] = (bf16_t)(ge * vg);
            }
}

// ---------------- Flash attention (causal), bf16 in/out ----------------
// Q is pre-scaled by 1/sqrt(HD). Layout: [b, t, h*128+d] row-major ([4096, 2048]).
// Block: 4 waves; Q-tile 64 rows (wave w owns rows 16w..16w+15); KV-tile 64.
__global__ __launch_bounds__(256)
void attn_kernel(const bf16_t* __restrict__ Q, const bf16_t* __restrict__ K,
                 const bf16_t* __restrict__ V, bf16_t* __restrict__ Z)
{
    const int qt = blockIdx.x, h = blockIdx.y, b = blockIdx.z;
    const int q0 = qt * 64;
    const int tid = threadIdx.x, wave = tid >> 6, lane = tid & 63;
    const int lr = lane & 15, lg = lane >> 4;

    __shared__ __align__(16) bf16_t Qs[64 * 128];
    __shared__ __align__(16) bf16_t Ks[64 * 128];
    __shared__ __align__(16) bf16_t Vt[128 * 64];   // transposed V: Vt[d][s]
    __shared__ __align__(16) bf16_t Ps[4][16 * 64]; // per-wave P scratch

    const size_t base = ((size_t)b * SEQ) * D_MODEL + (size_t)h * HEAD_D;

    #pragma unroll
    for (int i = 0; i < 4; ++i) {
        int v = tid + 256 * i;           // 64 rows x 16 vec8 = 1024
        int row = v >> 4, cv = (v & 15) * 8;
        *(uint4*)&Qs[row * 128 + cv] = *(const uint4*)&Q[base + (size_t)(q0 + row) * D_MODEL + cv];
    }

    f32x4 o[8] = {};
    float mrun[4], lrun[4];
    #pragma unroll
    for (int r = 0; r < 4; ++r) { mrun[r] = -1e30f; lrun[r] = 0.f; }

    for (int kt = 0; kt <= qt; ++kt) {
        const int k0 = kt * 64;
        __syncthreads();
        #pragma unroll
        for (int i = 0; i < 4; ++i) {
            int v = tid + 256 * i;
            int row = v >> 4, cv = (v & 15) * 8;
            *(uint4*)&Ks[row * 128 + cv] = *(const uint4*)&K[base + (size_t)(k0 + row) * D_MODEL + cv];
            bf16x8 vv = *(const bf16x8*)&V[base + (size_t)(k0 + row) * D_MODEL + cv];
            #pragma unroll
            for (int j = 0; j < 8; ++j) Vt[(cv + j) * 64 + row] = vv[j];
        }
        __syncthreads();

        // S = Q K^T (this wave: 16 rows x 64 cols)
        f32x4 s[4] = {};
        #pragma unroll
        for (int kk = 0; kk < 4; ++kk) {
            bf16x8 aq = *(const bf16x8*)&Qs[(wave * 16 + lr) * 128 + kk * 32 + lg * 8];
            #pragma unroll
            for (int nb = 0; nb < 4; ++nb) {
                bf16x8 bk = *(const bf16x8*)&Ks[(nb * 16 + lr) * 128 + kk * 32 + lg * 8];
                s[nb] = __builtin_amdgcn_mfma_f32_16x16x32_bf16(aq, bk, s[nb], 0, 0, 0);
            }
        }
        if (kt == qt) {  // diagonal tile: causal mask (k0 == q0)
            #pragma unroll
            for (int nb = 0; nb < 4; ++nb)
                #pragma unroll
                for (int r = 0; r < 4; ++r) {
                    int qrel = 16 * wave + lg * 4 + r;
                    int krel = nb * 16 + lr;
                    if (krel > qrel) s[nb][r] = -1e30f;
                }
        }
        // online softmax (rows replicated across each 16-lane group)
        float resc[4];
        #pragma unroll
        for (int r = 0; r < 4; ++r) {
            float mx = fmaxf(fmaxf(s[0][r], s[1][r]), fmaxf(s[2][r], s[3][r]));
            #pragma unroll
            for (int off = 1; off < 16; off <<= 1) mx = fmaxf(mx, __shfl_xor(mx, off));
            float mnew = fmaxf(mrun[r], mx);
            resc[r] = __expf(mrun[r] - mnew);
            float sum = 0.f;
            #pragma unroll
            for (int nb = 0; nb < 4; ++nb) {
                float p = __expf(s[nb][r] - mnew);
                s[nb][r] = p;
                sum += p;
            }
            #pragma unroll
            for (int off = 1; off < 16; off <<= 1) sum += __shfl_xor(sum, off);
            lrun[r] = lrun[r] * resc[r] + sum;
            mrun[r] = mnew;
        }
        #pragma unroll
        for (int ob = 0; ob < 8; ++ob)
            #pragma unroll
            for (int r = 0; r < 4; ++r) o[ob][r] *= resc[r];
        // P -> LDS (bf16, per-wave region), then PV
        #pragma unroll
        for (int nb = 0; nb < 4; ++nb)
            #pragma unroll
            for (int r = 0; r < 4; ++r)
                Ps[wave][(lg * 4 + r) * 64 + nb * 16 + lr] = (bf16_t)s[nb][r];
        #pragma unroll
        for (int kk = 0; kk < 2; ++kk) {
            bf16x8 ap = *(const bf16x8*)&Ps[wave][lr * 64 + kk * 32 + lg * 8];
            #pragma unroll
            for (int ob = 0; ob < 8; ++ob) {
                bf16x8 bv = *(const bf16x8*)&Vt[(ob * 16 + lr) * 64 + kk * 32 + lg * 8];
                o[ob] = __builtin_amdgcn_mfma_f32_16x16x32_bf16(ap, bv, o[ob], 0, 0, 0);
            }
        }
    }
    #pragma unroll
    for (int ob = 0; ob < 8; ++ob)
        #pragma unroll
        for (int r = 0; r < 4; ++r) {
            int t = q0 + 16 * wave + lg * 4 + r;
            Z[base + (size_t)t * D_MODEL + ob * 16 + lr] = (bf16_t)(o[ob][r] / lrun[r]);
        }
}

// ---------------- host launch ----------------
extern "C" void kernel_launch(void* const* d_in, const int* in_sizes, int n_in,
                              void* d_out, int out_size, void* d_ws, size_t ws_size,
                              hipStream_t stream)
{
    const float* x   = (const float*)d_in[0];
    const float* g1  = (const float*)d_in[1];
    const float* wq  = (const float*)d_in[2];
    const float* wk  = (const float*)d_in[3];
    const float* wv  = (const float*)d_in[4];
    const float* wo  = (const float*)d_in[5];
    const float* g2  = (const float*)d_in[6];
    const float* wup = (const float*)d_in[7];
    const float* wdn = (const float*)d_in[8];
    float* out = (float*)d_out;

    char* wsp = (char*)d_ws;
    size_t off = 0;
    auto alloc = [&](size_t bytes) { void* p = wsp + off; off += (bytes + 255) & ~255ull; return p; };
    bf16_t* wq_b  = (bf16_t*)alloc((size_t)D_MODEL * D_MODEL * 2);
    bf16_t* wk_b  = (bf16_t*)alloc((size_t)D_MODEL * D_MODEL * 2);
    bf16_t* wv_b  = (bf16_t*)alloc((size_t)D_MODEL * D_MODEL * 2);
    bf16_t* wo_b  = (bf16_t*)alloc((size_t)D_MODEL * D_MODEL * 2);
    bf16_t* wup_b = (bf16_t*)alloc((size_t)UPN * D_MODEL * 2);
    bf16_t* wdn_b = (bf16_t*)alloc((size_t)D_MODEL * DFF * 2);
    bf16_t* h_b   = (bf16_t*)alloc((size_t)NTOK * D_MODEL * 2);
    bf16_t* q_b   = (bf16_t*)alloc((size_t)NTOK * D_MODEL * 2);
    bf16_t* k_b   = (bf16_t*)alloc((size_t)NTOK * D_MODEL * 2);
    bf16_t* v_b   = (bf16_t*)alloc((size_t)NTOK * D_MODEL * 2);
    bf16_t* z_b   = (bf16_t*)alloc((size_t)NTOK * D_MODEL * 2);
    float*  x1    = (float*) alloc((size_t)NTOK * D_MODEL * 4);
    bf16_t* h2_b  = (bf16_t*)alloc((size_t)NTOK * D_MODEL * 2);
    bf16_t* act_b = (bf16_t*)alloc((size_t)NTOK * DFF * 2);

    auto cvt = [&](const float* in, bf16_t* outb, long n) {
        long n4 = n / 4;
        long nb = (n4 + 255) / 256;
        int blocks = nb > 2048 ? 2048 : (int)nb;
        cvt_bf16_kernel<<<blocks, 256, 0, stream>>>(in, outb, n4);
    };
    cvt(wq,  wq_b,  (long)D_MODEL * D_MODEL);
    cvt(wk,  wk_b,  (long)D_MODEL * D_MODEL);
    cvt(wv,  wv_b,  (long)D_MODEL * D_MODEL);
    cvt(wo,  wo_b,  (long)D_MODEL * D_MODEL);
    cvt(wup, wup_b, (long)UPN * D_MODEL);
    cvt(wdn, wdn_b, (long)D_MODEL * DFF);

    // h = rmsnorm(x, g1)
    rmsnorm_kernel<<<NTOK, 256, 0, stream>>>(x, g1, h_b);

    // q,k,v GEMMs (q pre-scaled by 1/sqrt(HD))
    dim3 g_qkv(D_MODEL / 128, NTOK / 128);
    gemm_bt<0><<<g_qkv, 256, 0, stream>>>(h_b, wq_b, q_b, nullptr, NTOK, D_MODEL, D_MODEL, 0.08838834764831845f);
    gemm_bt<0><<<g_qkv, 256, 0, stream>>>(h_b, wk_b, k_b, nullptr, NTOK, D_MODEL, D_MODEL, 1.0f);
    gemm_bt<0><<<g_qkv, 256, 0, stream>>>(h_b, wv_b, v_b, nullptr, NTOK, D_MODEL, D_MODEL, 1.0f);

    // attention
    attn_kernel<<<dim3(SEQ / 64, N_HEADS, 2), 256, 0, stream>>>(q_b, k_b, v_b, z_b);

    // x1 = x + z @ wo^T
    gemm_bt<1><<<g_qkv, 256, 0, stream>>>(z_b, wo_b, x1, x, NTOK, D_MODEL, D_MODEL, 1.0f);

    // h2 = rmsnorm(x1, g2)
    rmsnorm_kernel<<<NTOK, 256, 0, stream>>>(x1, g2, h2_b);

    // act = gelu(h2 @ Wu^T) * (h2 @ Wv^T)
    gemm_upgate<<<dim3(DFF / 64, NTOK / 128), 256, 0, stream>>>(h2_b, wup_b, act_b);

    // out = x1 + act @ w_down^T
    gemm_bt<1><<<dim3(D_MODEL / 128, NTOK / 128), 256, 0, stream>>>(act_b, wdn_b, out, x1, NTOK, D_MODEL, DFF, 1.0f);
}

// Round 2
// 1074.577 us; speedup vs baseline: 1.3250x; 1.3250x over previous
//
#include <hip/hip_runtime.h>
#include <math.h>

typedef __bf16 bf16_t;
typedef __bf16 bf16x8 __attribute__((ext_vector_type(8)));
typedef __bf16 bf16x4 __attribute__((ext_vector_type(4)));
typedef float f32x4 __attribute__((ext_vector_type(4)));

#define D_MODEL 2048
#define N_HEADS 16
#define HEAD_D 128
#define SEQ 2048
#define NTOK 4096   // B*T = 2*2048
#define DFF 8192    // D*MULT
#define UPN 16384   // 2*D*MULT

#define GLDS16(g, l) __builtin_amdgcn_global_load_lds( \
    (const __attribute__((address_space(1))) void*)(g), \
    (__attribute__((address_space(3))) void*)(l), 16, 0, 0)

// ---------------- f32 -> bf16 convert (vectorized, grid-stride) ----------------
__global__ __launch_bounds__(256) void cvt_bf16_kernel(const float* __restrict__ in,
                                                       bf16_t* __restrict__ out, long n4) {
    long i = (long)blockIdx.x * 256 + threadIdx.x;
    long stride = (long)gridDim.x * 256;
    for (; i < n4; i += stride) {
        float4 f = ((const float4*)in)[i];
        bf16x4 v;
        v[0] = (bf16_t)f.x; v[1] = (bf16_t)f.y; v[2] = (bf16_t)f.z; v[3] = (bf16_t)f.w;
        ((bf16x4*)out)[i] = v;
    }
}

// ---------------- RMSNorm: one block per row of 2048, bf16 out ----------------
__global__ __launch_bounds__(256) void rmsnorm_kernel(const float* __restrict__ x,
                                                      const float* __restrict__ g,
                                                      bf16_t* __restrict__ out) {
    int row = blockIdx.x;
    const float* xr = x + (size_t)row * D_MODEL;
    int c0 = threadIdx.x * 8;
    float4 a = *(const float4*)&xr[c0];
    float4 b = *(const float4*)&xr[c0 + 4];
    float ss = a.x*a.x + a.y*a.y + a.z*a.z + a.w*a.w
             + b.x*b.x + b.y*b.y + b.z*b.z + b.w*b.w;
    #pragma unroll
    for (int off = 1; off < 64; off <<= 1) ss += __shfl_xor(ss, off);
    __shared__ float red[4];
    if ((threadIdx.x & 63) == 0) red[threadIdx.x >> 6] = ss;
    __syncthreads();
    float norm = rsqrtf((red[0] + red[1] + red[2] + red[3]) * (1.f / D_MODEL) + 1e-6f);
    float4 ga = *(const float4*)&g[c0];
    float4 gb = *(const float4*)&g[c0 + 4];
    bf16x8 o;
    o[0] = (bf16_t)(a.x * ga.x * norm); o[1] = (bf16_t)(a.y * ga.y * norm);
    o[2] = (bf16_t)(a.z * ga.z * norm); o[3] = (bf16_t)(a.w * ga.w * norm);
    o[4] = (bf16_t)(b.x * gb.x * norm); o[5] = (bf16_t)(b.y * gb.y * norm);
    o[6] = (bf16_t)(b.z * gb.z * norm); o[7] = (bf16_t)(b.w * gb.w * norm);
    *(bf16x8*)&out[(size_t)row * D_MODEL + c0] = o;
}

// ---------------- GEMM: C[M,N] = A[M,K] @ W[N,K]^T (row-major bf16) ----------------
// EPI 0: out bf16 = acc*alpha.
// EPI 1: out f32 = res + acc.
// EPI 2: out bf16 scattered to [b,h,d,s] layout (for V^T) — row=token, col=feature.
template<int EPI>
__global__ __launch_bounds__(256)
void gemm_bt(const bf16_t* __restrict__ A, const bf16_t* __restrict__ W,
             void* __restrict__ outp, const float* __restrict__ res,
             int M, int N, int K, float alpha)
{
    __shared__ __align__(16) bf16_t As[128 * 32];
    __shared__ __align__(16) bf16_t Bs[128 * 32];
    const int tid = threadIdx.x;
    const int m0 = blockIdx.y * 128, n0 = blockIdx.x * 128;
    const int wave = tid >> 6, lane = tid & 63;
    const int wr = wave >> 1, wc = wave & 1;     // 2x2 wave grid, 64x64 per wave
    const int lr = lane & 15, lg = lane >> 4;
    const int srow = (lane >> 2), scol = (lane & 3) * 8;   // staging: 4 lanes/row
    f32x4 acc[4][4] = {};
    for (int k0 = 0; k0 < K; k0 += 32) {
        __syncthreads();
        #pragma unroll
        for (int t = 0; t < 2; ++t) {
            int rbase = wave * 32 + t * 16;
            int r = rbase + srow;
            GLDS16(&A[(size_t)(m0 + r) * K + k0 + scol], &As[rbase * 32]);
            GLDS16(&W[(size_t)(n0 + r) * K + k0 + scol], &Bs[rbase * 32]);
        }
        __syncthreads();
        bf16x8 af[4], bfr[4];
        #pragma unroll
        for (int m = 0; m < 4; ++m) af[m] = *(const bf16x8*)&As[(wr * 64 + m * 16 + lr) * 32 + lg * 8];
        #pragma unroll
        for (int n = 0; n < 4; ++n) bfr[n] = *(const bf16x8*)&Bs[(wc * 64 + n * 16 + lr) * 32 + lg * 8];
        #pragma unroll
        for (int m = 0; m < 4; ++m)
            #pragma unroll
            for (int n = 0; n < 4; ++n)
                acc[m][n] = __builtin_amdgcn_mfma_f32_16x16x32_bf16(af[m], bfr[n], acc[m][n], 0, 0, 0);
    }
    #pragma unroll
    for (int m = 0; m < 4; ++m)
        #pragma unroll
        for (int n = 0; n < 4; ++n) {
            int row = m0 + wr * 64 + m * 16 + lg * 4;
            int col = n0 + wc * 64 + n * 16 + lr;
            #pragma unroll
            for (int r = 0; r < 4; ++r) {
                float v = acc[m][n][r];
                if (EPI == 0) {
                    ((bf16_t*)outp)[(size_t)(row + r) * N + col] = (bf16_t)(v * alpha);
                } else if (EPI == 1) {
                    size_t idx = (size_t)(row + r) * N + col;
                    ((float*)outp)[idx] = res[idx] + v;
                } else {
                    int gr = row + r;  // token index (b*2048 + t)
                    size_t idx = ((size_t)((gr >> 11) * 16 + (col >> 7)) * 128 + (col & 127)) * 2048
                               + (gr & 2047);
                    ((bf16_t*)outp)[idx] = (bf16_t)v;
                }
            }
        }
}

// ---------------- Up-projection with fused GELU gate ----------------
__global__ __launch_bounds__(256)
void gemm_upgate(const bf16_t* __restrict__ A, const bf16_t* __restrict__ W,
                 bf16_t* __restrict__ act)
{
    __shared__ __align__(16) bf16_t As[128 * 32];
    __shared__ __align__(16) bf16_t Bu[64 * 32];
    __shared__ __align__(16) bf16_t Bv[64 * 32];
    const int tid = threadIdx.x;
    const int m0 = blockIdx.y * 128, n0 = blockIdx.x * 64;
    const int wave = tid >> 6, lane = tid & 63;
    const int wr = wave >> 1, wc = wave & 1;     // per wave: 64 rows x 32 cols (u and v)
    const int lr = lane & 15, lg = lane >> 4;
    const int srow = (lane >> 2), scol = (lane & 3) * 8;
    f32x4 accu[4][2] = {}, accv[4][2] = {};
    for (int k0 = 0; k0 < D_MODEL; k0 += 32) {
        __syncthreads();
        #pragma unroll
        for (int t = 0; t < 2; ++t) {
            int rbase = wave * 32 + t * 16;
            GLDS16(&A[(size_t)(m0 + rbase + srow) * D_MODEL + k0 + scol], &As[rbase * 32]);
        }
        {
            int rbase = wave * 16;
            GLDS16(&W[(size_t)(n0 + rbase + srow) * D_MODEL + k0 + scol], &Bu[rbase * 32]);
            GLDS16(&W[(size_t)(DFF + n0 + rbase + srow) * D_MODEL + k0 + scol], &Bv[rbase * 32]);
        }
        __syncthreads();
        bf16x8 af[4], bu[2], bv[2];
        #pragma unroll
        for (int m = 0; m < 4; ++m) af[m] = *(const bf16x8*)&As[(wr * 64 + m * 16 + lr) * 32 + lg * 8];
        #pragma unroll
        for (int n = 0; n < 2; ++n) {
            bu[n] = *(const bf16x8*)&Bu[(wc * 32 + n * 16 + lr) * 32 + lg * 8];
            bv[n] = *(const bf16x8*)&Bv[(wc * 32 + n * 16 + lr) * 32 + lg * 8];
        }
        #pragma unroll
        for (int m = 0; m < 4; ++m)
            #pragma unroll
            for (int n = 0; n < 2; ++n) {
                accu[m][n] = __builtin_amdgcn_mfma_f32_16x16x32_bf16(af[m], bu[n], accu[m][n], 0, 0, 0);
                accv[m][n] = __builtin_amdgcn_mfma_f32_16x16x32_bf16(af[m], bv[n], accv[m][n], 0, 0, 0);
            }
    }
    #pragma unroll
    for (int m = 0; m < 4; ++m)
        #pragma unroll
        for (int n = 0; n < 2; ++n)
            #pragma unroll
            for (int r = 0; r < 4; ++r) {
                int row = m0 + wr * 64 + m * 16 + lg * 4 + r;
                int col = n0 + wc * 32 + n * 16 + lr;
                float u = accu[m][n][r], vg = accv[m][n][r];
                float ge = 0.5f * u * (1.f + erff(u * 0.70710678118654752f));
                act[(size_t)row * DFF + col] = (bf16_t)(ge * vg);
            }
}

// ---------------- Flash attention (causal), bf16 in/out ----------------
// Q pre-scaled by 1/sqrt(HD). Q,K,Z layout [b*T + t][h*128+d]; Vt layout [b,h,d,s].
// Block: 4 waves; Q-tile 64 (wave w owns rows 16w..16w+15); KV-tile 64.
// LDS strides padded: 136 (Q/K rows of 128), 72 (Vt/Ps rows of 64) — kills bank conflicts.
__global__ __launch_bounds__(256)
void attn_kernel(const bf16_t* __restrict__ Q, const bf16_t* __restrict__ K,
                 const bf16_t* __restrict__ Vt, bf16_t* __restrict__ Z)
{
    const int qt = gridDim.x - 1 - blockIdx.x;   // long blocks launch first
    const int h = blockIdx.y, b = blockIdx.z;
    const int q0 = qt * 64;
    const int tid = threadIdx.x, wave = tid >> 6, lane = tid & 63;
    const int lr = lane & 15, lg = lane >> 4;

    __shared__ __align__(16) bf16_t Qs[64 * 136];
    __shared__ __align__(16) bf16_t Ks[64 * 136];
    __shared__ __align__(16) bf16_t Vts[128 * 72];
    __shared__ __align__(16) bf16_t Ps[4][16 * 72];

    const size_t base = ((size_t)b * SEQ) * D_MODEL + (size_t)h * HEAD_D;
    const size_t vbase = (size_t)(b * N_HEADS + h) * HEAD_D * SEQ;

    #pragma unroll
    for (int i = 0; i < 4; ++i) {
        int v = tid + 256 * i;           // 64 rows x 16 vec8
        int row = v >> 4, cv = (v & 15) * 8;
        *(uint4*)&Qs[row * 136 + cv] = *(const uint4*)&Q[base + (size_t)(q0 + row) * D_MODEL + cv];
    }

    f32x4 o[8] = {};
    float mrun[4], lrun[4];
    #pragma unroll
    for (int r = 0; r < 4; ++r) { mrun[r] = -1e30f; lrun[r] = 0.f; }

    for (int kt = 0; kt <= qt; ++kt) {
        const int k0 = kt * 64;
        __syncthreads();
        #pragma unroll
        for (int i = 0; i < 4; ++i) {
            int v = tid + 256 * i;
            int row = v >> 4, cv = (v & 15) * 8;
            *(uint4*)&Ks[row * 136 + cv] = *(const uint4*)&K[base + (size_t)(k0 + row) * D_MODEL + cv];
            int d = v >> 3, c8 = (v & 7) * 8;   // 128 d-rows x 8 vec8
            *(uint4*)&Vts[d * 72 + c8] = *(const uint4*)&Vt[vbase + (size_t)d * SEQ + k0 + c8];
        }
        __syncthreads();

        // S = Q K^T (this wave: 16 rows x 64 cols)
        f32x4 s[4] = {};
        #pragma unroll
        for (int kk = 0; kk < 4; ++kk) {
            bf16x8 aq = *(const bf16x8*)&Qs[(wave * 16 + lr) * 136 + kk * 32 + lg * 8];
            #pragma unroll
            for (int nb = 0; nb < 4; ++nb) {
                bf16x8 bk = *(const bf16x8*)&Ks[(nb * 16 + lr) * 136 + kk * 32 + lg * 8];
                s[nb] = __builtin_amdgcn_mfma_f32_16x16x32_bf16(aq, bk, s[nb], 0, 0, 0);
            }
        }
        if (kt == qt) {  // diagonal tile: causal mask
            #pragma unroll
            for (int nb = 0; nb < 4; ++nb)
                #pragma unroll
                for (int r = 0; r < 4; ++r) {
                    int qrel = 16 * wave + lg * 4 + r;
                    int krel = nb * 16 + lr;
                    if (krel > qrel) s[nb][r] = -1e30f;
                }
        }
        // online softmax (rows replicated across each 16-lane group)
        float resc[4];
        #pragma unroll
        for (int r = 0; r < 4; ++r) {
            float mx = fmaxf(fmaxf(s[0][r], s[1][r]), fmaxf(s[2][r], s[3][r]));
            #pragma unroll
            for (int off = 1; off < 16; off <<= 1) mx = fmaxf(mx, __shfl_xor(mx, off));
            float mnew = fmaxf(mrun[r], mx);
            resc[r] = __expf(mrun[r] - mnew);
            float sum = 0.f;
            #pragma unroll
            for (int nb = 0; nb < 4; ++nb) {
                float p = __expf(s[nb][r] - mnew);
                s[nb][r] = p;
                sum += p;
            }
            #pragma unroll
            for (int off = 1; off < 16; off <<= 1) sum += __shfl_xor(sum, off);
            lrun[r] = lrun[r] * resc[r] + sum;
            mrun[r] = mnew;
        }
        #pragma unroll
        for (int ob = 0; ob < 8; ++ob)
            #pragma unroll
            for (int r = 0; r < 4; ++r) o[ob][r] *= resc[r];
        // P -> LDS (bf16, per-wave region, stride 72), then PV
        #pragma unroll
        for (int nb = 0; nb < 4; ++nb)
            #pragma unroll
            for (int r = 0; r < 4; ++r)
                Ps[wave][(lg * 4 + r) * 72 + nb * 16 + lr] = (bf16_t)s[nb][r];
        #pragma unroll
        for (int kk = 0; kk < 2; ++kk) {
            bf16x8 ap = *(const bf16x8*)&Ps[wave][lr * 72 + kk * 32 + lg * 8];
            #pragma unroll
            for (int ob = 0; ob < 8; ++ob) {
                bf16x8 bv = *(const bf16x8*)&Vts[(ob * 16 + lr) * 72 + kk * 32 + lg * 8];
                o[ob] = __builtin_amdgcn_mfma_f32_16x16x32_bf16(ap, bv, o[ob], 0, 0, 0);
            }
        }
    }
    #pragma unroll
    for (int ob = 0; ob < 8; ++ob)
        #pragma unroll
        for (int r = 0; r < 4; ++r) {
            int t = q0 + 16 * wave + lg * 4 + r;
            Z[base + (size_t)t * D_MODEL + ob * 16 + lr] = (bf16_t)(o[ob][r] / lrun[r]);
        }
}

// ---------------- host launch ----------------
extern "C" void kernel_launch(void* const* d_in, const int* in_sizes, int n_in,
                              void* d_out, int out_size, void* d_ws, size_t ws_size,
                              hipStream_t stream)
{
    const float* x   = (const float*)d_in[0];
    const float* g1  = (const float*)d_in[1];
    const float* wq  = (const float*)d_in[2];
    const float* wk  = (const float*)d_in[3];
    const float* wv  = (const float*)d_in[4];
    const float* wo  = (const float*)d_in[5];
    const float* g2  = (const float*)d_in[6];
    const float* wup = (const float*)d_in[7];
    const float* wdn = (const float*)d_in[8];
    float* out = (float*)d_out;

    char* wsp = (char*)d_ws;
    size_t off = 0;
    auto alloc = [&](size_t bytes) { void* p = wsp + off; off += (bytes + 255) & ~255ull; return p; };
    bf16_t* wq_b  = (bf16_t*)alloc((size_t)D_MODEL * D_MODEL * 2);
    bf16_t* wk_b  = (bf16_t*)alloc((size_t)D_MODEL * D_MODEL * 2);
    bf16_t* wv_b  = (bf16_t*)alloc((size_t)D_MODEL * D_MODEL * 2);
    bf16_t* wo_b  = (bf16_t*)alloc((size_t)D_MODEL * D_MODEL * 2);
    bf16_t* wup_b = (bf16_t*)alloc((size_t)UPN * D_MODEL * 2);
    bf16_t* wdn_b = (bf16_t*)alloc((size_t)D_MODEL * DFF * 2);
    bf16_t* h_b   = (bf16_t*)alloc((size_t)NTOK * D_MODEL * 2);
    bf16_t* q_b   = (bf16_t*)alloc((size_t)NTOK * D_MODEL * 2);
    bf16_t* k_b   = (bf16_t*)alloc((size_t)NTOK * D_MODEL * 2);
    bf16_t* vt_b  = (bf16_t*)alloc((size_t)NTOK * D_MODEL * 2);   // [b,h,d,s]
    bf16_t* z_b   = (bf16_t*)alloc((size_t)NTOK * D_MODEL * 2);
    float*  x1    = (float*) alloc((size_t)NTOK * D_MODEL * 4);
    bf16_t* h2_b  = (bf16_t*)alloc((size_t)NTOK * D_MODEL * 2);
    bf16_t* act_b = (bf16_t*)alloc((size_t)NTOK * DFF * 2);

    auto cvt = [&](const float* in, bf16_t* outb, long n) {
        long n4 = n / 4;
        long nb = (n4 + 255) / 256;
        int blocks = nb > 2048 ? 2048 : (int)nb;
        cvt_bf16_kernel<<<blocks, 256, 0, stream>>>(in, outb, n4);
    };
    cvt(wq,  wq_b,  (long)D_MODEL * D_MODEL);
    cvt(wk,  wk_b,  (long)D_MODEL * D_MODEL);
    cvt(wv,  wv_b,  (long)D_MODEL * D_MODEL);
    cvt(wo,  wo_b,  (long)D_MODEL * D_MODEL);
    cvt(wup, wup_b, (long)UPN * D_MODEL);
    cvt(wdn, wdn_b, (long)D_MODEL * DFF);

    // h = rmsnorm(x, g1)
    rmsnorm_kernel<<<NTOK, 256, 0, stream>>>(x, g1, h_b);

    // q,k GEMMs (q pre-scaled by 1/sqrt(HD)); v GEMM writes V^T [b,h,d,s] directly
    dim3 g_qkv(D_MODEL / 128, NTOK / 128);
    gemm_bt<0><<<g_qkv, 256, 0, stream>>>(h_b, wq_b, q_b, nullptr, NTOK, D_MODEL, D_MODEL, 0.08838834764831845f);
    gemm_bt<0><<<g_qkv, 256, 0, stream>>>(h_b, wk_b, k_b, nullptr, NTOK, D_MODEL, D_MODEL, 1.0f);
    gemm_bt<2><<<g_qkv, 256, 0, stream>>>(h_b, wv_b, vt_b, nullptr, NTOK, D_MODEL, D_MODEL, 1.0f);

    // attention
    attn_kernel<<<dim3(SEQ / 64, N_HEADS, 2), 256, 0, stream>>>(q_b, k_b, vt_b, z_b);

    // x1 = x + z @ wo^T
    gemm_bt<1><<<g_qkv, 256, 0, stream>>>(z_b, wo_b, x1, x, NTOK, D_MODEL, D_MODEL, 1.0f);

    // h2 = rmsnorm(x1, g2)
    rmsnorm_kernel<<<NTOK, 256, 0, stream>>>(x1, g2, h2_b);

    // act = gelu(h2 @ Wu^T) * (h2 @ Wv^T)
    gemm_upgate<<<dim3(DFF / 64, NTOK / 128), 256, 0, stream>>>(h2_b, wup_b, act_b);

    // out = x1 + act @ w_down^T
    gemm_bt<1><<<dim3(D_MODEL / 128, NTOK / 128), 256, 0, stream>>>(act_b, wdn_b, out, x1, NTOK, D_MODEL, DFF, 1.0f);
}

// Round 3
// 1022.943 us; speedup vs baseline: 1.3919x; 1.0505x over previous
//
#include <hip/hip_runtime.h>
#include <math.h>

typedef __bf16 bf16_t;
typedef __bf16 bf16x8 __attribute__((ext_vector_type(8)));
typedef __bf16 bf16x4 __attribute__((ext_vector_type(4)));
typedef float f32x4 __attribute__((ext_vector_type(4)));

#define D_MODEL 2048
#define N_HEADS 16
#define HEAD_D 128
#define SEQ 2048
#define NTOK 4096   // B*T = 2*2048
#define DFF 8192    // D*MULT
#define UPN 16384   // 2*D*MULT

#define GLDS16(g, l) __builtin_amdgcn_global_load_lds( \
    (const __attribute__((address_space(1))) void*)(g), \
    (__attribute__((address_space(3))) void*)(l), 16, 0, 0)

// ---------------- f32 -> bf16 convert ----------------
__global__ __launch_bounds__(256) void cvt_bf16_kernel(const float* __restrict__ in,
                                                       bf16_t* __restrict__ out, long n4) {
    long i = (long)blockIdx.x * 256 + threadIdx.x;
    long stride = (long)gridDim.x * 256;
    for (; i < n4; i += stride) {
        float4 f = ((const float4*)in)[i];
        bf16x4 v;
        v[0] = (bf16_t)f.x; v[1] = (bf16_t)f.y; v[2] = (bf16_t)f.z; v[3] = (bf16_t)f.w;
        ((bf16x4*)out)[i] = v;
    }
}

// ---------------- RMSNorm ----------------
__global__ __launch_bounds__(256) void rmsnorm_kernel(const float* __restrict__ x,
                                                      const float* __restrict__ g,
                                                      bf16_t* __restrict__ out) {
    int row = blockIdx.x;
    const float* xr = x + (size_t)row * D_MODEL;
    int c0 = threadIdx.x * 8;
    float4 a = *(const float4*)&xr[c0];
    float4 b = *(const float4*)&xr[c0 + 4];
    float ss = a.x*a.x + a.y*a.y + a.z*a.z + a.w*a.w
             + b.x*b.x + b.y*b.y + b.z*b.z + b.w*b.w;
    #pragma unroll
    for (int off = 1; off < 64; off <<= 1) ss += __shfl_xor(ss, off);
    __shared__ float red[4];
    if ((threadIdx.x & 63) == 0) red[threadIdx.x >> 6] = ss;
    __syncthreads();
    float norm = rsqrtf((red[0] + red[1] + red[2] + red[3]) * (1.f / D_MODEL) + 1e-6f);
    float4 ga = *(const float4*)&g[c0];
    float4 gb = *(const float4*)&g[c0 + 4];
    bf16x8 o;
    o[0] = (bf16_t)(a.x * ga.x * norm); o[1] = (bf16_t)(a.y * ga.y * norm);
    o[2] = (bf16_t)(a.z * ga.z * norm); o[3] = (bf16_t)(a.w * ga.w * norm);
    o[4] = (bf16_t)(b.x * gb.x * norm); o[5] = (bf16_t)(b.y * gb.y * norm);
    o[6] = (bf16_t)(b.z * gb.z * norm); o[7] = (bf16_t)(b.w * gb.w * norm);
    *(bf16x8*)&out[(size_t)row * D_MODEL + c0] = o;
}

// ---------------- 8-phase 256x128 GEMM (counted-vmcnt pipeline) ----------------
// C[M,128-block] = A[M,K] @ W[*,K]^T. 512 threads = 8 waves (4M x 2N), wave owns 64x64.
// LDS: A tile 256x64 (2 halves) + B tile 128x64 (1 half; MODE2: +Bv half), double-buffered.
// Swizzle: element ^= (row&7)<<3 on reads; inverse-applied on global source for GLDS.
// MODE 0: fused QKV (W = wq|wk|wv contiguous, N=6144). q scaled; v scatter to [b,h,d,s].
// MODE 1: f32 out = res + acc (N=2048).
// MODE 2: upgate pairs (Bu=W rows n, Bv=W rows 8192+n): act = gelu(u)*v, N-pairs=8192.
__device__ __forceinline__ void stage_half(const bf16_t* gbase, int ldK,
                                           bf16_t* lds_half, int wave, int lane) {
    #pragma unroll
    for (int i = 0; i < 2; ++i) {
        int rl = i * 64 + wave * 8 + (lane >> 3);
        int cb = ((lane & 7) ^ (lane >> 3)) << 4;          // inverse-swizzled source byte col
        const char* src = (const char*)(gbase + (size_t)rl * ldK) + cb;
        char* dst = (char*)lds_half + i * 8192 + wave * 1024; // wave-uniform dest
        GLDS16(src, dst);
    }
}

template<int MODE>
__global__ __launch_bounds__(512)
void gemm8(const bf16_t* __restrict__ A, const bf16_t* __restrict__ W,
           void* __restrict__ o0, void* __restrict__ o1, void* __restrict__ o2,
           const float* __restrict__ res, int nbx, int K)
{
    __shared__ __align__(16) bf16_t As[2][256 * 64];
    __shared__ __align__(16) bf16_t Bs[2][(MODE == 2 ? 2 : 1) * 128 * 64];

    const int tid = threadIdx.x;
    const int wave = tid >> 6, lane = tid & 63;
    const int lr = lane & 15, lg = lane >> 4;
    const int wm = wave >> 1, wn = wave & 1;

    // bijective XCD swizzle (grid sizes are multiples of 8)
    const int nwg = gridDim.x, bid = blockIdx.x;
    const int cpx = nwg >> 3;
    const int s = (bid & 7) * cpx + (bid >> 3);
    const int bx = s % nbx, by = s / nbx;
    const int bm0 = by * 256, bn0 = bx * 128;

    const bf16_t* Asrc0 = A + (size_t)bm0 * K;
    const bf16_t* Asrc1 = A + (size_t)(bm0 + 128) * K;
    const bf16_t* Bsrc0 = W + (size_t)bn0 * K;
    const bf16_t* Bsrc1 = (MODE == 2) ? (W + (size_t)(DFF + bn0) * K) : nullptr;

    auto issue = [&](int t) {
        int p = t & 1;
        size_t k0 = (size_t)t * 64;
        stage_half(Asrc0 + k0, K, &As[p][0], wave, lane);
        stage_half(Asrc1 + k0, K, &As[p][128 * 64], wave, lane);
        stage_half(Bsrc0 + k0, K, &Bs[p][0], wave, lane);
        if constexpr (MODE == 2)
            stage_half(Bsrc1 + k0, K, &Bs[p][128 * 64], wave, lane);
    };

    f32x4 accu[4][4] = {};
    f32x4 accv[4][4] = {};   // used only in MODE 2 (dead otherwise)

    const int NKT = K >> 6;
    issue(0);
    for (int j = 0; j < NKT; ++j) {
        if (j + 1 < NKT) {
            issue(j + 1);
            if constexpr (MODE == 2) asm volatile("s_waitcnt vmcnt(8)" ::: "memory");
            else                     asm volatile("s_waitcnt vmcnt(6)" ::: "memory");
        } else {
            asm volatile("s_waitcnt vmcnt(0)" ::: "memory");
        }
        __builtin_amdgcn_s_barrier();

        const bf16_t* Ap = &As[j & 1][0];
        const bf16_t* Bp = &Bs[j & 1][0];

        bf16x8 af[4][2];
        #pragma unroll
        for (int m = 0; m < 4; ++m) {
            int row = wm * 64 + m * 16 + lr;
            #pragma unroll
            for (int kk = 0; kk < 2; ++kk)
                af[m][kk] = *(const bf16x8*)&Ap[row * 64 + ((kk * 32 + lg * 8) ^ ((row & 7) << 3))];
        }

        #pragma unroll
        for (int qn = 0; qn < 2; ++qn) {
            if constexpr (MODE != 2) {
                bf16x8 bfr[2][2];
                #pragma unroll
                for (int n2 = 0; n2 < 2; ++n2) {
                    int brow = wn * 64 + (qn * 2 + n2) * 16 + lr;
                    #pragma unroll
                    for (int kk = 0; kk < 2; ++kk)
                        bfr[n2][kk] = *(const bf16x8*)&Bp[brow * 64 + ((kk * 32 + lg * 8) ^ ((brow & 7) << 3))];
                }
                __builtin_amdgcn_s_setprio(1);
                #pragma unroll
                for (int m = 0; m < 4; ++m)
                    #pragma unroll
                    for (int n2 = 0; n2 < 2; ++n2)
                        #pragma unroll
                        for (int kk = 0; kk < 2; ++kk)
                            accu[m][qn * 2 + n2] = __builtin_amdgcn_mfma_f32_16x16x32_bf16(
                                af[m][kk], bfr[n2][kk], accu[m][qn * 2 + n2], 0, 0, 0);
                __builtin_amdgcn_s_setprio(0);
                __builtin_amdgcn_s_barrier();
            } else {
                #pragma unroll
                for (int qv = 0; qv < 2; ++qv) {
                    const bf16_t* Bpq = Bp + qv * (128 * 64);
                    bf16x8 bfr[2][2];
                    #pragma unroll
                    for (int n2 = 0; n2 < 2; ++n2) {
                        int brow = wn * 64 + (qn * 2 + n2) * 16 + lr;
                        #pragma unroll
                        for (int kk = 0; kk < 2; ++kk)
                            bfr[n2][kk] = *(const bf16x8*)&Bpq[brow * 64 + ((kk * 32 + lg * 8) ^ ((brow & 7) << 3))];
                    }
                    f32x4 (*accp)[4] = qv ? accv : accu;
                    __builtin_amdgcn_s_setprio(1);
                    #pragma unroll
                    for (int m = 0; m < 4; ++m)
                        #pragma unroll
                        for (int n2 = 0; n2 < 2; ++n2)
                            #pragma unroll
                            for (int kk = 0; kk < 2; ++kk)
                                accp[m][qn * 2 + n2] = __builtin_amdgcn_mfma_f32_16x16x32_bf16(
                                    af[m][kk], bfr[n2][kk], accp[m][qn * 2 + n2], 0, 0, 0);
                    __builtin_amdgcn_s_setprio(0);
                    __builtin_amdgcn_s_barrier();
                }
            }
        }
    }

    // ---------------- epilogue ----------------
    const int r0 = lg * 4;
    if constexpr (MODE == 0) {
        const float qs = 0.08838834764831845f;
        const int th = bn0 >> 11;   // block-uniform third: 0=q, 1=k, 2=v
        #pragma unroll
        for (int m = 0; m < 4; ++m) {
            int grow = bm0 + wm * 64 + m * 16 + r0;
            #pragma unroll
            for (int n = 0; n < 4; ++n) {
                int gcol = bn0 + wn * 64 + n * 16 + lr;
                int c = gcol & 2047;
                if (th == 0) {
                    #pragma unroll
                    for (int r = 0; r < 4; ++r)
                        ((bf16_t*)o0)[(size_t)(grow + r) * D_MODEL + c] = (bf16_t)(accu[m][n][r] * qs);
                } else if (th == 1) {
                    #pragma unroll
                    for (int r = 0; r < 4; ++r)
                        ((bf16_t*)o1)[(size_t)(grow + r) * D_MODEL + c] = (bf16_t)accu[m][n][r];
                } else {
                    int hh = c >> 7, d = c & 127;
                    int bb = grow >> 11, t0 = grow & 2047;
                    bf16x4 st;
                    #pragma unroll
                    for (int r = 0; r < 4; ++r) st[r] = (bf16_t)accu[m][n][r];
                    *(bf16x4*)&((bf16_t*)o2)[((size_t)(bb * N_HEADS + hh) * HEAD_D + d) * SEQ + t0] = st;
                }
            }
        }
    } else if constexpr (MODE == 1) {
        #pragma unroll
        for (int m = 0; m < 4; ++m) {
            int grow = bm0 + wm * 64 + m * 16 + r0;
            #pragma unroll
            for (int n = 0; n < 4; ++n) {
                int gcol = bn0 + wn * 64 + n * 16 + lr;
                #pragma unroll
                for (int r = 0; r < 4; ++r) {
                    size_t idx = (size_t)(grow + r) * D_MODEL + gcol;
                    ((float*)o0)[idx] = res[idx] + accu[m][n][r];
                }
            }
        }
    } else {
        #pragma unroll
        for (int m = 0; m < 4; ++m) {
            int grow = bm0 + wm * 64 + m * 16 + r0;
            #pragma unroll
            for (int n = 0; n < 4; ++n) {
                int gcol = bn0 + wn * 64 + n * 16 + lr;
                #pragma unroll
                for (int r = 0; r < 4; ++r) {
                    float u = accu[m][n][r], vg = accv[m][n][r];
                    float ge = 0.5f * u * (1.f + erff(u * 0.70710678118654752f));
                    ((bf16_t*)o0)[(size_t)(grow + r) * DFF + gcol] = (bf16_t)(ge * vg);
                }
            }
        }
    }
}

// ---------------- Flash attention (causal), bf16 in/out ----------------
__global__ __launch_bounds__(256)
void attn_kernel(const bf16_t* __restrict__ Q, const bf16_t* __restrict__ K,
                 const bf16_t* __restrict__ Vt, bf16_t* __restrict__ Z)
{
    const int qt = gridDim.x - 1 - blockIdx.x;   // long blocks launch first
    const int h = blockIdx.y, b = blockIdx.z;
    const int q0 = qt * 64;
    const int tid = threadIdx.x, wave = tid >> 6, lane = tid & 63;
    const int lr = lane & 15, lg = lane >> 4;

    __shared__ __align__(16) bf16_t Qs[64 * 136];
    __shared__ __align__(16) bf16_t Ks[64 * 136];
    __shared__ __align__(16) bf16_t Vts[128 * 72];
    __shared__ __align__(16) bf16_t Ps[4][16 * 72];

    const size_t base = ((size_t)b * SEQ) * D_MODEL + (size_t)h * HEAD_D;
    const size_t vbase = (size_t)(b * N_HEADS + h) * HEAD_D * SEQ;

    #pragma unroll
    for (int i = 0; i < 4; ++i) {
        int v = tid + 256 * i;
        int row = v >> 4, cv = (v & 15) * 8;
        *(uint4*)&Qs[row * 136 + cv] = *(const uint4*)&Q[base + (size_t)(q0 + row) * D_MODEL + cv];
    }

    f32x4 o[8] = {};
    float mrun[4], lrun[4];
    #pragma unroll
    for (int r = 0; r < 4; ++r) { mrun[r] = -1e30f; lrun[r] = 0.f; }

    for (int kt = 0; kt <= qt; ++kt) {
        const int k0 = kt * 64;
        __syncthreads();
        #pragma unroll
        for (int i = 0; i < 4; ++i) {
            int v = tid + 256 * i;
            int row = v >> 4, cv = (v & 15) * 8;
            *(uint4*)&Ks[row * 136 + cv] = *(const uint4*)&K[base + (size_t)(k0 + row) * D_MODEL + cv];
            int d = v >> 3, c8 = (v & 7) * 8;
            *(uint4*)&Vts[d * 72 + c8] = *(const uint4*)&Vt[vbase + (size_t)d * SEQ + k0 + c8];
        }
        __syncthreads();

        f32x4 s[4] = {};
        #pragma unroll
        for (int kk = 0; kk < 4; ++kk) {
            bf16x8 aq = *(const bf16x8*)&Qs[(wave * 16 + lr) * 136 + kk * 32 + lg * 8];
            #pragma unroll
            for (int nb = 0; nb < 4; ++nb) {
                bf16x8 bk = *(const bf16x8*)&Ks[(nb * 16 + lr) * 136 + kk * 32 + lg * 8];
                s[nb] = __builtin_amdgcn_mfma_f32_16x16x32_bf16(aq, bk, s[nb], 0, 0, 0);
            }
        }
        if (kt == qt) {
            #pragma unroll
            for (int nb = 0; nb < 4; ++nb)
                #pragma unroll
                for (int r = 0; r < 4; ++r) {
                    int qrel = 16 * wave + lg * 4 + r;
                    int krel = nb * 16 + lr;
                    if (krel > qrel) s[nb][r] = -1e30f;
                }
        }
        float resc[4];
        #pragma unroll
        for (int r = 0; r < 4; ++r) {
            float mx = fmaxf(fmaxf(s[0][r], s[1][r]), fmaxf(s[2][r], s[3][r]));
            #pragma unroll
            for (int off = 1; off < 16; off <<= 1) mx = fmaxf(mx, __shfl_xor(mx, off));
            float mnew = fmaxf(mrun[r], mx);
            resc[r] = __expf(mrun[r] - mnew);
            float sum = 0.f;
            #pragma unroll
            for (int nb = 0; nb < 4; ++nb) {
                float p = __expf(s[nb][r] - mnew);
                s[nb][r] = p;
                sum += p;
            }
            #pragma unroll
            for (int off = 1; off < 16; off <<= 1) sum += __shfl_xor(sum, off);
            lrun[r] = lrun[r] * resc[r] + sum;
            mrun[r] = mnew;
        }
        #pragma unroll
        for (int ob = 0; ob < 8; ++ob)
            #pragma unroll
            for (int r = 0; r < 4; ++r) o[ob][r] *= resc[r];
        #pragma unroll
        for (int nb = 0; nb < 4; ++nb)
            #pragma unroll
            for (int r = 0; r < 4; ++r)
                Ps[wave][(lg * 4 + r) * 72 + nb * 16 + lr] = (bf16_t)s[nb][r];
        #pragma unroll
        for (int kk = 0; kk < 2; ++kk) {
            bf16x8 ap = *(const bf16x8*)&Ps[wave][lr * 72 + kk * 32 + lg * 8];
            #pragma unroll
            for (int ob = 0; ob < 8; ++ob) {
                bf16x8 bv = *(const bf16x8*)&Vts[(ob * 16 + lr) * 72 + kk * 32 + lg * 8];
                o[ob] = __builtin_amdgcn_mfma_f32_16x16x32_bf16(ap, bv, o[ob], 0, 0, 0);
            }
        }
    }
    #pragma unroll
    for (int ob = 0; ob < 8; ++ob)
        #pragma unroll
        for (int r = 0; r < 4; ++r) {
            int t = q0 + 16 * wave + lg * 4 + r;
            Z[base + (size_t)t * D_MODEL + ob * 16 + lr] = (bf16_t)(o[ob][r] / lrun[r]);
        }
}

// ---------------- host launch ----------------
extern "C" void kernel_launch(void* const* d_in, const int* in_sizes, int n_in,
                              void* d_out, int out_size, void* d_ws, size_t ws_size,
                              hipStream_t stream)
{
    const float* x   = (const float*)d_in[0];
    const float* g1  = (const float*)d_in[1];
    const float* wq  = (const float*)d_in[2];
    const float* wk  = (const float*)d_in[3];
    const float* wv  = (const float*)d_in[4];
    const float* wo  = (const float*)d_in[5];
    const float* g2  = (const float*)d_in[6];
    const float* wup = (const float*)d_in[7];
    const float* wdn = (const float*)d_in[8];
    float* out = (float*)d_out;

    char* wsp = (char*)d_ws;
    size_t off = 0;
    auto alloc = [&](size_t bytes) { void* p = wsp + off; off += (bytes + 255) & ~255ull; return p; };
    // NOTE: wq_b/wk_b/wv_b must stay contiguous (fused QKV treats them as [6144][2048])
    bf16_t* wq_b  = (bf16_t*)alloc((size_t)D_MODEL * D_MODEL * 2);
    bf16_t* wk_b  = (bf16_t*)alloc((size_t)D_MODEL * D_MODEL * 2);
    bf16_t* wv_b  = (bf16_t*)alloc((size_t)D_MODEL * D_MODEL * 2);
    bf16_t* wo_b  = (bf16_t*)alloc((size_t)D_MODEL * D_MODEL * 2);
    bf16_t* wup_b = (bf16_t*)alloc((size_t)UPN * D_MODEL * 2);
    bf16_t* wdn_b = (bf16_t*)alloc((size_t)D_MODEL * DFF * 2);
    bf16_t* h_b   = (bf16_t*)alloc((size_t)NTOK * D_MODEL * 2);
    bf16_t* q_b   = (bf16_t*)alloc((size_t)NTOK * D_MODEL * 2);
    bf16_t* k_b   = (bf16_t*)alloc((size_t)NTOK * D_MODEL * 2);
    bf16_t* vt_b  = (bf16_t*)alloc((size_t)NTOK * D_MODEL * 2);   // [b,h,d,s]
    bf16_t* z_b   = (bf16_t*)alloc((size_t)NTOK * D_MODEL * 2);
    float*  x1    = (float*) alloc((size_t)NTOK * D_MODEL * 4);
    bf16_t* h2_b  = (bf16_t*)alloc((size_t)NTOK * D_MODEL * 2);
    bf16_t* act_b = (bf16_t*)alloc((size_t)NTOK * DFF * 2);

    auto cvt = [&](const float* in, bf16_t* outb, long n) {
        long n4 = n / 4;
        long nb = (n4 + 255) / 256;
        int blocks = nb > 2048 ? 2048 : (int)nb;
        cvt_bf16_kernel<<<blocks, 256, 0, stream>>>(in, outb, n4);
    };
    cvt(wq,  wq_b,  (long)D_MODEL * D_MODEL);
    cvt(wk,  wk_b,  (long)D_MODEL * D_MODEL);
    cvt(wv,  wv_b,  (long)D_MODEL * D_MODEL);
    cvt(wo,  wo_b,  (long)D_MODEL * D_MODEL);
    cvt(wup, wup_b, (long)UPN * D_MODEL);
    cvt(wdn, wdn_b, (long)D_MODEL * DFF);

    // h = rmsnorm(x, g1)
    rmsnorm_kernel<<<NTOK, 256, 0, stream>>>(x, g1, h_b);

    // fused QKV: N = 6144 (wq|wk|wv contiguous). q scaled; v scattered to [b,h,d,s].
    gemm8<0><<<48 * 16, 512, 0, stream>>>(h_b, wq_b, q_b, k_b, vt_b, nullptr, 48, D_MODEL);

    // attention
    attn_kernel<<<dim3(SEQ / 64, N_HEADS, 2), 256, 0, stream>>>(q_b, k_b, vt_b, z_b);

    // x1 = x + z @ wo^T
    gemm8<1><<<16 * 16, 512, 0, stream>>>(z_b, wo_b, x1, nullptr, nullptr, x, 16, D_MODEL);

    // h2 = rmsnorm(x1, g2)
    rmsnorm_kernel<<<NTOK, 256, 0, stream>>>(x1, g2, h2_b);

    // act = gelu(h2 @ Wu^T) * (h2 @ Wv^T)   (paired u/v per block)
    gemm8<2><<<64 * 16, 512, 0, stream>>>(h2_b, wup_b, act_b, nullptr, nullptr, nullptr, 64, D_MODEL);

    // out = x1 + act @ w_down^T
    gemm8<1><<<16 * 16, 512, 0, stream>>>(act_b, wdn_b, out, nullptr, nullptr, x1, 16, DFF);
}